// Round 7
// baseline (720.616 us; speedup 1.0000x reference)
//
#include <hip/hip_runtime.h>

// R12: R11 post-mortem — CSR math was right (first check passed); failure was
// the 80MB ebuf overflowing the workspace (proven budget ~31MB) and corrupting
// neighbors across replays. Also: totals never tracked edge gains; the ~190us
// remainder is the node side, dominated by the u*9-strided xout scatter
// (~18 lines/store-inst) + acc round-trip.
// Fix: CSR perm (4B/edge) + FULL FUSION: one kernel runs R10's reg-weight edge
// GEMV engine over dst-ordered edges, accumulates I/A/S in registers, runs the
// node pipeline in-wave, and writes X via LDS-transpose coalesced stores.
// No atomics (float), no acc buffer, no ebuf. Workspace 6.2MB.

#define EPW 8

// ---------------------------------------------------------------------------
// Prepass 1: per-TYPE halves of the We2 GEMV.
// ---------------------------------------------------------------------------
__global__ void ptype_kernel(const float* __restrict__ emb,
                             const float* __restrict__ We2,
                             const float* __restrict__ be2,
                             float* __restrict__ Pt1, float* __restrict__ Pt2) {
    const int c = threadIdx.x & 31;
    const int t = blockIdx.x * 8 + (threadIdx.x >> 5);
    if (t < 95) {
        float p1 = 0.f, p2 = 0.f;
        for (int k = 0; k < 32; ++k) {
            const float z = emb[t * 32 + k];
            p1 = fmaf(z, We2[k * 32 + c], p1);
            p2 = fmaf(z, We2[(32 + k) * 32 + c], p2);
        }
        Pt1[t * 32 + c] = p1 + be2[c];
        Pt2[t * 32 + c] = p2;
    }
}

// ---------------------------------------------------------------------------
// Prepass 2: gather per-node P1/P2; zero histogram.
// ---------------------------------------------------------------------------
__global__ void prep_kernel(const int* __restrict__ nt,
                            const float* __restrict__ Pt1, const float* __restrict__ Pt2,
                            float* __restrict__ P1, float* __restrict__ P2,
                            int* __restrict__ hist, int N) {
    const int i = blockIdx.x * 256 + threadIdx.x;
    if (i < N) hist[i] = 0;
    if (i < N * 32) {
        const int n = i >> 5, c = i & 31;
        const int t = nt[n];
        P1[i] = Pt1[t * 32 + c];
        P2[i] = Pt2[t * 32 + c];
    }
}

__global__ void hist_kernel(const int* __restrict__ dst, int* __restrict__ hist, int E) {
    const int i = blockIdx.x * 256 + threadIdx.x;
    if (i < E) atomicAdd(&hist[dst[i]], 1);
}

// Single-wave exclusive scan -> base[0..N], cursor copy.
__global__ void scan_kernel(const int* __restrict__ hist,
                            int* __restrict__ base, int* __restrict__ cursor,
                            int N, int E) {
    const int lane = threadIdx.x;   // 64 threads
    int carry = 0;
    for (int start = 0; start < N; start += 64) {
        const int i = start + lane;
        const int v = (i < N) ? hist[i] : 0;
        int inc = v;
#pragma unroll
        for (int o = 1; o < 64; o <<= 1) {
            const int t = __shfl_up(inc, o, 64);
            if (lane >= o) inc += t;
        }
        const int excl = carry + inc - v;
        if (i < N) { base[i] = excl; cursor[i] = excl; }
        carry += __shfl(inc, 63, 64);
    }
    if (lane == 0) base[N] = E;
}

// perm[slot] = edge id, slots binned by dst (one int atomic per edge).
__global__ void binperm_kernel(const int* __restrict__ dst, int* __restrict__ cursor,
                               int* __restrict__ perm, int E) {
    const int i = blockIdx.x * 256 + threadIdx.x;
    if (i < E) {
        const int s = atomicAdd(&cursor[dst[i]], 1);
        perm[s] = i;
    }
}

// ---------------------------------------------------------------------------
// Fused kernel [R12]: wave-per-node, grid-stride.
//  Edge phase (per 8-edge chunk of this node's CSR run): R10 engine —
//   weights in 128 VGPRs (k-half h per lane), x rows staged in per-wave LDS,
//   uniform b128 broadcasts, 1024 FMA/chunk; epilogue accumulates I/A/S into
//   10 per-lane registers (no atomics, no intermediate buffers).
//  Node phase: LN + MLP via width-32 shuffles, mixing via LDS-staged packed
//   weights, X written via LDS transpose -> coalesced 64-lane stores.
// NO VGPR cap (R8 lesson). The only __syncthreads is the weight-staging one.
// ---------------------------------------------------------------------------
__global__ __launch_bounds__(256) void fused_kernel(
    const float* __restrict__ edge_attr,    // [E][64]
    const float* __restrict__ bond_dist,    // [E]
    const float* __restrict__ bond_vec,     // [E][3]
    const int*   __restrict__ src,
    const float* __restrict__ Wd1, const float* __restrict__ bd1,
    const float* __restrict__ Wd2, const float* __restrict__ bd2,
    const float* __restrict__ Wd3, const float* __restrict__ bd3,
    const float* __restrict__ We3, const float* __restrict__ be3,
    const float* __restrict__ P1,           // [N][32]
    const float* __restrict__ P2,           // [N][32]
    const int*   __restrict__ basep,        // [N+1]
    const int*   __restrict__ perm,         // [E]
    const float* __restrict__ Wt0, const float* __restrict__ Wt1, const float* __restrict__ Wt2,
    const float* __restrict__ Ws1, const float* __restrict__ bs1,
    const float* __restrict__ Ws2, const float* __restrict__ bs2,
    const float* __restrict__ lng, const float* __restrict__ lnb,
    float* __restrict__ xout,               // [N][32][3][3]
    float* __restrict__ efeat,              // [E][32]
    int N)
{
    __shared__ float4 sX[4][8][16];         // 8 KB  per-wave x-tile / x-out scratch
    __shared__ float4 wtp[32][32];          // 16 KB {Wt0,Wt1,Wt2,-}
    __shared__ float2 ws1p[32][32];         // 8 KB
    __shared__ float4 ws2p[64][32];         // 32 KB
    __shared__ float4 accS4[4][32][3];      // 6 KB  per-wave acc tile
    __shared__ float2 sb1p[32];
    __shared__ float4 sb2p[32];
    __shared__ float  sg[32], sbv[32];

    const int tid = threadIdx.x;
    for (int i = tid; i < 1024; i += 256) {
        const int k = i >> 5, u = i & 31;
        wtp[k][u]  = make_float4(Wt0[i], Wt1[i], Wt2[i], 0.f);
        ws1p[k][u] = make_float2(Ws1[k * 64 + u], Ws1[k * 64 + 32 + u]);
    }
    for (int i = tid; i < 2048; i += 256) {
        const int k = i >> 5, u = i & 31;
        ws2p[k][u] = make_float4(Ws2[k * 96 + 3 * u], Ws2[k * 96 + 3 * u + 1],
                                 Ws2[k * 96 + 3 * u + 2], 0.f);
    }
    if (tid < 32) {
        sb1p[tid] = make_float2(bs1[tid], bs1[tid + 32]);
        sb2p[tid] = make_float4(bs2[3 * tid], bs2[3 * tid + 1], bs2[3 * tid + 2], 0.f);
        sg[tid] = lng[tid]; sbv[tid] = lnb[tid];
    }
    __syncthreads();   // the only barrier

    const int lane = tid & 63;
    const int c    = lane & 31;
    const int h    = lane >> 5;
    const int wv   = tid >> 6;

    // edge-GEMV weight columns for (c, k-half h) -> 128 VGPRs, loaded once
    float w0r[32], w1r[32], w2r[32], w3r[32];
#pragma unroll
    for (int kk = 0; kk < 32; ++kk) {
        const int row = (h << 5) + kk;
        w0r[kk] = Wd1[row * 32 + c];
        w1r[kk] = Wd2[row * 32 + c];
        w2r[kk] = Wd3[row * 32 + c];
        w3r[kk] = We3[row * 32 + c];
    }
    const float bd1r = bd1[c], bd2r = bd2[c], bd3r = bd3[c], be3r = be3[c];

    const int wgid  = blockIdx.x * 4 + wv;
    const int nwaves = gridDim.x * 4;

    for (int n = wgid; n < N; n += nwaves) {
        const int js = basep[n], je = basep[n + 1];
        const float pzn = P2[(size_t)n * 32 + c];

        float rc0 = 0, ra0 = 0, ra1 = 0, ra2 = 0;
        float rs00 = 0, rs01 = 0, rs02 = 0, rs11 = 0, rs12 = 0, rs22 = 0;

        for (int off = js; off < je; off += EPW) {
            // hoisted per-edge scalars for this half's 4 edges
            int eid4[4], si4[4]; float dd[4], vx[4], vy[4], vz[4]; bool vld[4];
#pragma unroll
            for (int jj = 0; jj < 4; ++jj) {
                int s_ = off + jj + (h << 2);
                vld[jj] = (s_ < je);
                if (s_ > je - 1) s_ = je - 1;
                const int eid = perm[s_];
                eid4[jj] = eid;
                si4[jj]  = src[eid];
                dd[jj]   = bond_dist[eid];
                vx[jj]   = bond_vec[3 * (size_t)eid + 0];
                vy[jj]   = bond_vec[3 * (size_t)eid + 1];
                vz[jj]   = bond_vec[3 * (size_t)eid + 2];
            }

            // stage up to 8 edge rows into per-wave LDS (no barrier: same-wave RAW)
            {
                int sa = off + (lane >> 4);     if (sa > je - 1) sa = je - 1;
                int sb = off + 4 + (lane >> 4); if (sb > je - 1) sb = je - 1;
                const int ea = perm[sa], eb = perm[sb];
                sX[wv][lane >> 4][lane & 15] =
                    *(const float4*)&edge_attr[(size_t)ea * 64 + (lane & 15) * 4];
                sX[wv][4 + (lane >> 4)][lane & 15] =
                    *(const float4*)&edge_attr[(size_t)eb * 64 + (lane & 15) * 4];
            }

            float A0[EPW], A1[EPW], A2[EPW], A3[EPW];
#pragma unroll
            for (int j = 0; j < EPW; ++j) { A0[j] = 0.f; A1[j] = 0.f; A2[j] = 0.f; A3[j] = 0.f; }

#pragma unroll
            for (int kq = 0; kq < 8; ++kq) {
                const int k0 = kq * 4;
#pragma unroll
                for (int j = 0; j < EPW; ++j) {
                    const float4 xq = sX[wv][j][(h << 3) + kq];
                    A0[j] = fmaf(xq.x, w0r[k0 + 0], A0[j]);
                    A0[j] = fmaf(xq.y, w0r[k0 + 1], A0[j]);
                    A0[j] = fmaf(xq.z, w0r[k0 + 2], A0[j]);
                    A0[j] = fmaf(xq.w, w0r[k0 + 3], A0[j]);
                    A1[j] = fmaf(xq.x, w1r[k0 + 0], A1[j]);
                    A1[j] = fmaf(xq.y, w1r[k0 + 1], A1[j]);
                    A1[j] = fmaf(xq.z, w1r[k0 + 2], A1[j]);
                    A1[j] = fmaf(xq.w, w1r[k0 + 3], A1[j]);
                    A2[j] = fmaf(xq.x, w2r[k0 + 0], A2[j]);
                    A2[j] = fmaf(xq.y, w2r[k0 + 1], A2[j]);
                    A2[j] = fmaf(xq.z, w2r[k0 + 2], A2[j]);
                    A2[j] = fmaf(xq.w, w2r[k0 + 3], A2[j]);
                    A3[j] = fmaf(xq.x, w3r[k0 + 0], A3[j]);
                    A3[j] = fmaf(xq.y, w3r[k0 + 1], A3[j]);
                    A3[j] = fmaf(xq.z, w3r[k0 + 2], A3[j]);
                    A3[j] = fmaf(xq.w, w3r[k0 + 3], A3[j]);
                }
            }

            float az4[4];
#pragma unroll
            for (int jj = 0; jj < 4; ++jj)
                az4[jj] = P1[(size_t)si4[jj] * 32 + c] + pzn;

#pragma unroll
            for (int jj = 0; jj < 4; ++jj) {
                const float sd0 = h ? A0[jj] : A0[jj + 4];
                const float sd1 = h ? A1[jj] : A1[jj + 4];
                const float sd2 = h ? A2[jj] : A2[jj + 4];
                const float sd3 = h ? A3[jj] : A3[jj + 4];
                const float mn0 = h ? A0[jj + 4] : A0[jj];
                const float mn1 = h ? A1[jj + 4] : A1[jj];
                const float mn2 = h ? A2[jj + 4] : A2[jj];
                const float mn3 = h ? A3[jj + 4] : A3[jj];
                const float t0 = mn0 + __shfl_xor(sd0, 32);
                const float t1 = mn1 + __shfl_xor(sd1, 32);
                const float t2 = mn2 + __shfl_xor(sd2, 32);
                const float t3 = mn3 + __shfl_xor(sd3, 32);

                const float d = dd[jj];
                const float C = (d <= 5.0f) ? 0.5f * (cosf(3.14159265358979323846f * d / 5.0f) + 1.0f) : 0.0f;
                float v0 = vx[jj], v1 = vy[jj], v2 = vz[jj];
                const float inv = 1.0f / sqrtf(v0 * v0 + v1 * v1 + v2 * v2);
                v0 *= inv; v1 *= inv; v2 *= inv;
                const float tr3 = (v0 * v0 + v1 * v1 + v2 * v2) * (1.0f / 3.0f);
                const float y00 = v0 * v0 - tr3, y11 = v1 * v1 - tr3, y22 = v2 * v2 - tr3;
                const float y01 = v0 * v1, y02 = v0 * v2, y12 = v1 * v2;

                const float az = az4[jj];
                const float a1v = t0 + bd1r;
                const float a2v = t1 + bd2r;
                const float a3v = t2 + bd3r;
                const float a4v = t3 + be3r;
                const float w1v = a1v * C, w2v = a2v * C, w3v = a3v * C;
                const float fI = az * w1v, fA = az * w2v, fS = az * w3v;

                if (vld[jj]) {
                    efeat[(size_t)eid4[jj] * 32 + c] = a4v;
                    rc0 += fI;
                    ra0 = fmaf(fA, v0, ra0);
                    ra1 = fmaf(fA, v1, ra1);
                    ra2 = fmaf(fA, v2, ra2);
                    rs00 = fmaf(fS, y00, rs00);
                    rs01 = fmaf(fS, y01, rs01);
                    rs02 = fmaf(fS, y02, rs02);
                    rs11 = fmaf(fS, y11, rs11);
                    rs12 = fmaf(fS, y12, rs12);
                    rs22 = fmaf(fS, y22, rs22);
                }
            }
        }

        // merge the two K-half edge sets
        rc0 += __shfl_xor(rc0, 32);  ra0 += __shfl_xor(ra0, 32);
        ra1 += __shfl_xor(ra1, 32);  ra2 += __shfl_xor(ra2, 32);
        rs00 += __shfl_xor(rs00, 32); rs01 += __shfl_xor(rs01, 32);
        rs02 += __shfl_xor(rs02, 32); rs11 += __shfl_xor(rs11, 32);
        rs12 += __shfl_xor(rs12, 32); rs22 += __shfl_xor(rs22, 32);

        // ---- node phase (both halves compute identically; h==0 writes) ----
        if (h == 0) {
            accS4[wv][c][0] = make_float4(rc0, ra0, ra1, ra2);
            accS4[wv][c][1] = make_float4(rs00, rs01, rs02, rs11);
            accS4[wv][c][2] = make_float4(rs12, rs22, 0.f, 0.f);
        }

        const float m00 = rc0 + rs00, m11 = rc0 + rs11, m22 = rc0 + rs22;
        float nrm = m00 * m00 + m11 * m11 + m22 * m22
                  + 2.0f * (rs01 * rs01 + ra2 * ra2 + rs02 * rs02
                            + ra1 * ra1 + rs12 * rs12 + ra0 * ra0);

        float sum = nrm;
#pragma unroll
        for (int o = 16; o >= 1; o >>= 1) sum += __shfl_xor(sum, o, 32);
        const float mu = sum * (1.0f / 32.0f);
        const float dv = nrm - mu;
        float vs = dv * dv;
#pragma unroll
        for (int o = 16; o >= 1; o >>= 1) vs += __shfl_xor(vs, o, 32);
        const float var = vs * (1.0f / 32.0f);
        const float nl = dv * rsqrtf(var + 1e-5f) * sg[c] + sbv[c];

        const float2 b1 = sb1p[c];
        float h1a = b1.x, h1b = b1.y;
#pragma unroll
        for (int k = 0; k < 32; ++k) {
            const float x = __shfl(nl, k, 32);
            const float2 wq = ws1p[k][c];
            h1a = fmaf(x, wq.x, h1a);
            h1b = fmaf(x, wq.y, h1b);
        }
        h1a = h1a / (1.0f + __expf(-h1a));
        h1b = h1b / (1.0f + __expf(-h1b));

        const float4 b2 = sb2p[c];
        float f0 = b2.x, f1 = b2.y, f2 = b2.z;
#pragma unroll
        for (int k = 0; k < 32; ++k) {
            const float hh = __shfl(h1a, k, 32);
            const float4 wq = ws2p[k][c];
            f0 = fmaf(hh, wq.x, f0);
            f1 = fmaf(hh, wq.y, f1);
            f2 = fmaf(hh, wq.z, f2);
        }
#pragma unroll
        for (int k = 0; k < 32; ++k) {
            const float hh = __shfl(h1b, k, 32);
            const float4 wq = ws2p[32 + k][c];
            f0 = fmaf(hh, wq.x, f0);
            f1 = fmaf(hh, wq.y, f1);
            f2 = fmaf(hh, wq.z, f2);
        }
        f0 = f0 / (1.0f + __expf(-f0));
        f1 = f1 / (1.0f + __expf(-f1));
        f2 = f2 / (1.0f + __expf(-f2));

        float m0 = 0, ma0 = 0, ma1 = 0, ma2 = 0;
        float ms00 = 0, ms01 = 0, ms02 = 0, ms11 = 0, ms12 = 0, ms22 = 0;
#pragma unroll
        for (int k = 0; k < 32; ++k) {
            const float4 w  = wtp[k][c];
            const float4 q0 = accS4[wv][k][0];
            const float4 q1 = accS4[wv][k][1];
            const float4 q2 = accS4[wv][k][2];
            m0   = fmaf(q0.x, w.x, m0);
            ma0  = fmaf(q0.y, w.y, ma0);
            ma1  = fmaf(q0.z, w.y, ma1);
            ma2  = fmaf(q0.w, w.y, ma2);
            ms00 = fmaf(q1.x, w.z, ms00);
            ms01 = fmaf(q1.y, w.z, ms01);
            ms02 = fmaf(q1.z, w.z, ms02);
            ms11 = fmaf(q1.w, w.z, ms11);
            ms12 = fmaf(q2.x, w.z, ms12);
            ms22 = fmaf(q2.y, w.z, ms22);
        }

        // X via LDS transpose -> coalesced stores (fixes the u*9 scatter)
        float* xs = (float*)&sX[wv][0][0];   // 1152B scratch, k-phase done
        if (h == 0) {
            xs[c * 9 + 0] = f0 * m0 + f2 * ms00;
            xs[c * 9 + 1] = f1 * (-ma2) + f2 * ms01;
            xs[c * 9 + 2] = f1 * ( ma1) + f2 * ms02;
            xs[c * 9 + 3] = f1 * ( ma2) + f2 * ms01;
            xs[c * 9 + 4] = f0 * m0 + f2 * ms11;
            xs[c * 9 + 5] = f1 * (-ma0) + f2 * ms12;
            xs[c * 9 + 6] = f1 * ( ma1) * 0.f + f1 * (-ma1) + f2 * ms02;  // = f1*(-ma1)+f2*ms02
            xs[c * 9 + 7] = f1 * ( ma0) + f2 * ms12;
            xs[c * 9 + 8] = f0 * m0 + f2 * ms22;
        }
        float* xp = xout + (size_t)n * 288;
#pragma unroll
        for (int i = 0; i < 5; ++i) {
            const int idx = lane + i * 64;
            if (idx < 288) xp[idx] = xs[idx];
        }
    }
}

extern "C" void kernel_launch(void* const* d_in, const int* in_sizes, int n_in,
                              void* d_out, int out_size, void* d_ws, size_t ws_size,
                              hipStream_t stream) {
    const int N = in_sizes[0];
    const int E = in_sizes[2];

    // Workspace (6.2 MB): P1 N*32 | P2 N*32 | Pt1 95*32 | Pt2 95*32 f32
    //                     | hist N | base N+1 | cursor N | perm E  i32
    float* P1   = (float*)d_ws;
    float* P2   = P1 + (size_t)N * 32;
    float* Pt1  = P2 + (size_t)N * 32;
    float* Pt2  = Pt1 + 95 * 32;
    int*   hist = (int*)(Pt2 + 95 * 32);
    int*   basep  = hist + N;
    int*   cursor = basep + (N + 1);
    int*   perm   = cursor + N;

    float* xout  = (float*)d_out;              // [N][32][3][3] f32
    float* efeat = xout + (size_t)N * 288;     // [E][32] f32

    ptype_kernel<<<12, 256, 0, stream>>>(
        (const float*)d_in[6], (const float*)d_in[13], (const float*)d_in[14], Pt1, Pt2);

    prep_kernel<<<(N * 32 + 255) / 256, 256, 0, stream>>>(
        (const int*)d_in[0], Pt1, Pt2, P1, P2, hist, N);

    hist_kernel<<<(E + 255) / 256, 256, 0, stream>>>(
        (const int*)d_in[5], hist, E);

    scan_kernel<<<1, 64, 0, stream>>>(hist, basep, cursor, N, E);

    binperm_kernel<<<(E + 255) / 256, 256, 0, stream>>>(
        (const int*)d_in[5], cursor, perm, E);

    fused_kernel<<<512, 256, 0, stream>>>(
        (const float*)d_in[1], (const float*)d_in[2], (const float*)d_in[3],
        (const int*)d_in[4],
        (const float*)d_in[7],  (const float*)d_in[8],
        (const float*)d_in[9],  (const float*)d_in[10],
        (const float*)d_in[11], (const float*)d_in[12],
        (const float*)d_in[15], (const float*)d_in[16],
        P1, P2, basep, perm,
        (const float*)d_in[17], (const float*)d_in[18], (const float*)d_in[19],
        (const float*)d_in[20], (const float*)d_in[21],
        (const float*)d_in[22], (const float*)d_in[23],
        (const float*)d_in[24], (const float*)d_in[25],
        xout, efeat, N);
}

// Round 8
// 574.212 us; speedup vs baseline: 1.2550x; 1.2550x over previous
//
#include <hip/hip_runtime.h>

// R13: R12 proved CSR + per-node register accumulation correct, but fusing
// edge GEMV (128 persistent weight VGPRs) with the node pipeline spilled
// (VGPR=256 pinned, FETCH 293MB vs 75 algorithmic). Split back into two
// kernels: edge_csr (R10 engine + plain coalesced acc stores, zero atomics)
// and node (R10 barrier-free + LDS-transpose X stores — the u*9 scatter was
// 162 write-transactions/node vs 18 ideal, the hidden ~190us).
// Workspace 31.8MB = R5-R8 proven budget. NO VGPR caps (R8 lesson).

#define EPW 8

// ---------------------------------------------------------------------------
// Prepass 1: per-TYPE halves of the We2 GEMV.
// ---------------------------------------------------------------------------
__global__ void ptype_kernel(const float* __restrict__ emb,
                             const float* __restrict__ We2,
                             const float* __restrict__ be2,
                             float* __restrict__ Pt1, float* __restrict__ Pt2) {
    const int c = threadIdx.x & 31;
    const int t = blockIdx.x * 8 + (threadIdx.x >> 5);
    if (t < 95) {
        float p1 = 0.f, p2 = 0.f;
        for (int k = 0; k < 32; ++k) {
            const float z = emb[t * 32 + k];
            p1 = fmaf(z, We2[k * 32 + c], p1);
            p2 = fmaf(z, We2[(32 + k) * 32 + c], p2);
        }
        Pt1[t * 32 + c] = p1 + be2[c];
        Pt2[t * 32 + c] = p2;
    }
}

// ---------------------------------------------------------------------------
// Prepass 2: gather per-node P1/P2; zero histogram.
// ---------------------------------------------------------------------------
__global__ void prep_kernel(const int* __restrict__ nt,
                            const float* __restrict__ Pt1, const float* __restrict__ Pt2,
                            float* __restrict__ P1, float* __restrict__ P2,
                            int* __restrict__ hist, int N) {
    const int i = blockIdx.x * 256 + threadIdx.x;
    if (i < N) hist[i] = 0;
    if (i < N * 32) {
        const int n = i >> 5, c = i & 31;
        const int t = nt[n];
        P1[i] = Pt1[t * 32 + c];
        P2[i] = Pt2[t * 32 + c];
    }
}

__global__ void hist_kernel(const int* __restrict__ dst, int* __restrict__ hist, int E) {
    const int i = blockIdx.x * 256 + threadIdx.x;
    if (i < E) atomicAdd(&hist[dst[i]], 1);
}

// Single-wave exclusive scan -> base[0..N], cursor copy.
__global__ void scan_kernel(const int* __restrict__ hist,
                            int* __restrict__ base, int* __restrict__ cursor,
                            int N, int E) {
    const int lane = threadIdx.x;   // 64 threads
    int carry = 0;
    for (int start = 0; start < N; start += 64) {
        const int i = start + lane;
        const int v = (i < N) ? hist[i] : 0;
        int inc = v;
#pragma unroll
        for (int o = 1; o < 64; o <<= 1) {
            const int t = __shfl_up(inc, o, 64);
            if (lane >= o) inc += t;
        }
        const int excl = carry + inc - v;
        if (i < N) { base[i] = excl; cursor[i] = excl; }
        carry += __shfl(inc, 63, 64);
    }
    if (lane == 0) base[N] = E;
}

// perm[slot] = edge id, slots binned by dst (one int atomic per edge).
__global__ void binperm_kernel(const int* __restrict__ dst, int* __restrict__ cursor,
                               int* __restrict__ perm, int E) {
    const int i = blockIdx.x * 256 + threadIdx.x;
    if (i < E) {
        const int s = atomicAdd(&cursor[dst[i]], 1);
        perm[s] = i;
    }
}

// ---------------------------------------------------------------------------
// Edge CSR kernel [R13]: wave-per-node, grid-stride. R10 reg-weight engine
// (128 weight VGPRs, per-wave LDS x-tile, uniform b128 broadcasts) over the
// node's dst-sorted edge run; I/A/S sums accumulate in 10 registers; epilogue
// is 5 plain coalesced 128B stores per half (NO atomics, no zero-pass).
// ---------------------------------------------------------------------------
__global__ __launch_bounds__(256) void edge_csr_kernel(
    const float* __restrict__ edge_attr,    // [E][64]
    const float* __restrict__ bond_dist,    // [E]
    const float* __restrict__ bond_vec,     // [E][3]
    const int*   __restrict__ src,
    const float* __restrict__ Wd1, const float* __restrict__ bd1,
    const float* __restrict__ Wd2, const float* __restrict__ bd2,
    const float* __restrict__ Wd3, const float* __restrict__ bd3,
    const float* __restrict__ We3, const float* __restrict__ be3,
    const float* __restrict__ P1,           // [N][32]
    const float* __restrict__ P2,           // [N][32]
    const int*   __restrict__ basep,        // [N+1]
    const int*   __restrict__ perm,         // [E]
    float* __restrict__ acc,                // [N][10][32]
    float* __restrict__ efeat,              // [E][32]
    int N)
{
    __shared__ float4 sX[4][8][16];         // per-wave x-tile

    const int tid  = threadIdx.x;
    const int lane = tid & 63;
    const int c    = lane & 31;
    const int h    = lane >> 5;
    const int wv   = tid >> 6;

    float w0r[32], w1r[32], w2r[32], w3r[32];
#pragma unroll
    for (int kk = 0; kk < 32; ++kk) {
        const int row = (h << 5) + kk;
        w0r[kk] = Wd1[row * 32 + c];
        w1r[kk] = Wd2[row * 32 + c];
        w2r[kk] = Wd3[row * 32 + c];
        w3r[kk] = We3[row * 32 + c];
    }
    const float bd1r = bd1[c], bd2r = bd2[c], bd3r = bd3[c], be3r = be3[c];

    const int wgid   = blockIdx.x * 4 + wv;
    const int nwaves = gridDim.x * 4;

    for (int n = wgid; n < N; n += nwaves) {
        const int js = basep[n], je = basep[n + 1];
        const float pzn = P2[(size_t)n * 32 + c];

        float rc0 = 0, ra0 = 0, ra1 = 0, ra2 = 0;
        float rs00 = 0, rs01 = 0, rs02 = 0, rs11 = 0, rs12 = 0, rs22 = 0;

        for (int off = js; off < je; off += EPW) {
            int eid4[4], si4[4]; float dd[4], vx[4], vy[4], vz[4]; bool vld[4];
#pragma unroll
            for (int jj = 0; jj < 4; ++jj) {
                int s_ = off + jj + (h << 2);
                vld[jj] = (s_ < je);
                if (s_ > je - 1) s_ = je - 1;
                const int eid = perm[s_];
                eid4[jj] = eid;
                si4[jj]  = src[eid];
                dd[jj]   = bond_dist[eid];
                vx[jj]   = bond_vec[3 * (size_t)eid + 0];
                vy[jj]   = bond_vec[3 * (size_t)eid + 1];
                vz[jj]   = bond_vec[3 * (size_t)eid + 2];
            }

            {
                int sa = off + (lane >> 4);     if (sa > je - 1) sa = je - 1;
                int sb = off + 4 + (lane >> 4); if (sb > je - 1) sb = je - 1;
                const int ea = perm[sa], eb = perm[sb];
                sX[wv][lane >> 4][lane & 15] =
                    *(const float4*)&edge_attr[(size_t)ea * 64 + (lane & 15) * 4];
                sX[wv][4 + (lane >> 4)][lane & 15] =
                    *(const float4*)&edge_attr[(size_t)eb * 64 + (lane & 15) * 4];
            }

            float A0[EPW], A1[EPW], A2[EPW], A3[EPW];
#pragma unroll
            for (int j = 0; j < EPW; ++j) { A0[j] = 0.f; A1[j] = 0.f; A2[j] = 0.f; A3[j] = 0.f; }

#pragma unroll
            for (int kq = 0; kq < 8; ++kq) {
                const int k0 = kq * 4;
#pragma unroll
                for (int j = 0; j < EPW; ++j) {
                    const float4 xq = sX[wv][j][(h << 3) + kq];
                    A0[j] = fmaf(xq.x, w0r[k0 + 0], A0[j]);
                    A0[j] = fmaf(xq.y, w0r[k0 + 1], A0[j]);
                    A0[j] = fmaf(xq.z, w0r[k0 + 2], A0[j]);
                    A0[j] = fmaf(xq.w, w0r[k0 + 3], A0[j]);
                    A1[j] = fmaf(xq.x, w1r[k0 + 0], A1[j]);
                    A1[j] = fmaf(xq.y, w1r[k0 + 1], A1[j]);
                    A1[j] = fmaf(xq.z, w1r[k0 + 2], A1[j]);
                    A1[j] = fmaf(xq.w, w1r[k0 + 3], A1[j]);
                    A2[j] = fmaf(xq.x, w2r[k0 + 0], A2[j]);
                    A2[j] = fmaf(xq.y, w2r[k0 + 1], A2[j]);
                    A2[j] = fmaf(xq.z, w2r[k0 + 2], A2[j]);
                    A2[j] = fmaf(xq.w, w2r[k0 + 3], A2[j]);
                    A3[j] = fmaf(xq.x, w3r[k0 + 0], A3[j]);
                    A3[j] = fmaf(xq.y, w3r[k0 + 1], A3[j]);
                    A3[j] = fmaf(xq.z, w3r[k0 + 2], A3[j]);
                    A3[j] = fmaf(xq.w, w3r[k0 + 3], A3[j]);
                }
            }

            float az4[4];
#pragma unroll
            for (int jj = 0; jj < 4; ++jj)
                az4[jj] = P1[(size_t)si4[jj] * 32 + c] + pzn;

#pragma unroll
            for (int jj = 0; jj < 4; ++jj) {
                const float sd0 = h ? A0[jj] : A0[jj + 4];
                const float sd1 = h ? A1[jj] : A1[jj + 4];
                const float sd2 = h ? A2[jj] : A2[jj + 4];
                const float sd3 = h ? A3[jj] : A3[jj + 4];
                const float mn0 = h ? A0[jj + 4] : A0[jj];
                const float mn1 = h ? A1[jj + 4] : A1[jj];
                const float mn2 = h ? A2[jj + 4] : A2[jj];
                const float mn3 = h ? A3[jj + 4] : A3[jj];
                const float t0 = mn0 + __shfl_xor(sd0, 32);
                const float t1 = mn1 + __shfl_xor(sd1, 32);
                const float t2 = mn2 + __shfl_xor(sd2, 32);
                const float t3 = mn3 + __shfl_xor(sd3, 32);

                const float d = dd[jj];
                const float C = (d <= 5.0f) ? 0.5f * (cosf(3.14159265358979323846f * d / 5.0f) + 1.0f) : 0.0f;
                float v0 = vx[jj], v1 = vy[jj], v2 = vz[jj];
                const float inv = 1.0f / sqrtf(v0 * v0 + v1 * v1 + v2 * v2);
                v0 *= inv; v1 *= inv; v2 *= inv;
                const float tr3 = (v0 * v0 + v1 * v1 + v2 * v2) * (1.0f / 3.0f);
                const float y00 = v0 * v0 - tr3, y11 = v1 * v1 - tr3, y22 = v2 * v2 - tr3;
                const float y01 = v0 * v1, y02 = v0 * v2, y12 = v1 * v2;

                const float az = az4[jj];
                const float a1v = t0 + bd1r;
                const float a2v = t1 + bd2r;
                const float a3v = t2 + bd3r;
                const float a4v = t3 + be3r;
                const float w1v = a1v * C, w2v = a2v * C, w3v = a3v * C;
                const float fI = az * w1v, fA = az * w2v, fS = az * w3v;

                if (vld[jj]) {
                    efeat[(size_t)eid4[jj] * 32 + c] = a4v;
                    rc0 += fI;
                    ra0 = fmaf(fA, v0, ra0);
                    ra1 = fmaf(fA, v1, ra1);
                    ra2 = fmaf(fA, v2, ra2);
                    rs00 = fmaf(fS, y00, rs00);
                    rs01 = fmaf(fS, y01, rs01);
                    rs02 = fmaf(fS, y02, rs02);
                    rs11 = fmaf(fS, y11, rs11);
                    rs12 = fmaf(fS, y12, rs12);
                    rs22 = fmaf(fS, y22, rs22);
                }
            }
        }

        // merge the two K-half edge sets
        rc0 += __shfl_xor(rc0, 32);  ra0 += __shfl_xor(ra0, 32);
        ra1 += __shfl_xor(ra1, 32);  ra2 += __shfl_xor(ra2, 32);
        rs00 += __shfl_xor(rs00, 32); rs01 += __shfl_xor(rs01, 32);
        rs02 += __shfl_xor(rs02, 32); rs11 += __shfl_xor(rs11, 32);
        rs12 += __shfl_xor(rs12, 32); rs22 += __shfl_xor(rs22, 32);

        // plain coalesced stores; this node is owned by exactly this wave
        float* ap = acc + (size_t)n * 320;
        if (h == 0) {
            ap[c]       = rc0;  ap[32 + c]  = ra0;  ap[64 + c]  = ra1;
            ap[96 + c]  = ra2;  ap[128 + c] = rs00;
        } else {
            ap[160 + c] = rs01; ap[192 + c] = rs02; ap[224 + c] = rs11;
            ap[256 + c] = rs12; ap[288 + c] = rs22;
        }
    }
}

// ---------------------------------------------------------------------------
// Node kernel [R13]: R10's barrier-free half-wave pipeline + LDS-transpose X
// stores (u*9 scatter was 162 write-transactions/node vs 18 ideal).
// ---------------------------------------------------------------------------
__global__ __launch_bounds__(256) void node_kernel(
    const float* __restrict__ acc,          // [N][10][32]
    const float* __restrict__ Wt0, const float* __restrict__ Wt1, const float* __restrict__ Wt2,
    const float* __restrict__ Ws1, const float* __restrict__ bs1,
    const float* __restrict__ Ws2, const float* __restrict__ bs2,
    const float* __restrict__ lng, const float* __restrict__ lnb,
    float* __restrict__ xout,               // [N][32][3][3]
    int N)
{
    __shared__ float4 wtp[32][32];          // 16 KB
    __shared__ float2 ws1p[32][32];         // 8 KB
    __shared__ float4 ws2p[64][32];         // 32 KB
    __shared__ float4 accS4[8][32][3];      // 12 KB (per half-wave private)
    __shared__ float  xsS[8][288];          // 9 KB  (per half-wave X scratch)
    __shared__ float2 sb1p[32];
    __shared__ float4 sb2p[32];
    __shared__ float  sg[32], sbv[32];

    const int tid = threadIdx.x;
    for (int i = tid; i < 1024; i += 256) {
        const int k = i >> 5, u = i & 31;
        wtp[k][u]  = make_float4(Wt0[i], Wt1[i], Wt2[i], 0.f);
        ws1p[k][u] = make_float2(Ws1[k * 64 + u], Ws1[k * 64 + 32 + u]);
    }
    for (int i = tid; i < 2048; i += 256) {
        const int k = i >> 5, u = i & 31;
        ws2p[k][u] = make_float4(Ws2[k * 96 + 3 * u], Ws2[k * 96 + 3 * u + 1],
                                 Ws2[k * 96 + 3 * u + 2], 0.f);
    }
    if (tid < 32) {
        sb1p[tid] = make_float2(bs1[tid], bs1[tid + 32]);
        sb2p[tid] = make_float4(bs2[3 * tid], bs2[3 * tid + 1], bs2[3 * tid + 2], 0.f);
        sg[tid] = lng[tid]; sbv[tid] = lnb[tid];
    }
    __syncthreads();   // the only barrier

    const int hw = tid >> 5, u = tid & 31;
    const int stride = gridDim.x * 8;

    for (int n = blockIdx.x * 8 + hw; n < N; n += stride) {
        const float* ap = acc + (size_t)n * 320 + u;
        const float c0 = ap[0],   a0 = ap[32],  a1 = ap[64],  a2 = ap[96];
        const float s00 = ap[128], s01 = ap[160], s02 = ap[192];
        const float s11 = ap[224], s12 = ap[256], s22 = ap[288];

        accS4[hw][u][0] = make_float4(c0, a0, a1, a2);
        accS4[hw][u][1] = make_float4(s00, s01, s02, s11);
        accS4[hw][u][2] = make_float4(s12, s22, 0.f, 0.f);

        const float m00 = c0 + s00, m11 = c0 + s11, m22 = c0 + s22;
        float nrm = m00 * m00 + m11 * m11 + m22 * m22
                  + 2.0f * (s01 * s01 + a2 * a2 + s02 * s02 + a1 * a1 + s12 * s12 + a0 * a0);

        float sum = nrm;
#pragma unroll
        for (int o = 16; o >= 1; o >>= 1) sum += __shfl_xor(sum, o, 32);
        const float mu = sum * (1.0f / 32.0f);
        const float dv = nrm - mu;
        float vs = dv * dv;
#pragma unroll
        for (int o = 16; o >= 1; o >>= 1) vs += __shfl_xor(vs, o, 32);
        const float var = vs * (1.0f / 32.0f);
        const float nl = dv * rsqrtf(var + 1e-5f) * sg[u] + sbv[u];

        const float2 b1 = sb1p[u];
        float h1a = b1.x, h1b = b1.y;
#pragma unroll
        for (int k = 0; k < 32; ++k) {
            const float x = __shfl(nl, k, 32);
            const float2 wq = ws1p[k][u];
            h1a = fmaf(x, wq.x, h1a);
            h1b = fmaf(x, wq.y, h1b);
        }
        h1a = h1a / (1.0f + __expf(-h1a));
        h1b = h1b / (1.0f + __expf(-h1b));

        const float4 b2 = sb2p[u];
        float f0 = b2.x, f1 = b2.y, f2 = b2.z;
#pragma unroll
        for (int k = 0; k < 32; ++k) {
            const float hh = __shfl(h1a, k, 32);
            const float4 wq = ws2p[k][u];
            f0 = fmaf(hh, wq.x, f0);
            f1 = fmaf(hh, wq.y, f1);
            f2 = fmaf(hh, wq.z, f2);
        }
#pragma unroll
        for (int k = 0; k < 32; ++k) {
            const float hh = __shfl(h1b, k, 32);
            const float4 wq = ws2p[32 + k][u];
            f0 = fmaf(hh, wq.x, f0);
            f1 = fmaf(hh, wq.y, f1);
            f2 = fmaf(hh, wq.z, f2);
        }
        f0 = f0 / (1.0f + __expf(-f0));
        f1 = f1 / (1.0f + __expf(-f1));
        f2 = f2 / (1.0f + __expf(-f2));

        float m0 = 0, ma0 = 0, ma1 = 0, ma2 = 0;
        float ms00 = 0, ms01 = 0, ms02 = 0, ms11 = 0, ms12 = 0, ms22 = 0;
#pragma unroll
        for (int k = 0; k < 32; ++k) {
            const float4 w  = wtp[k][u];
            const float4 q0 = accS4[hw][k][0];
            const float4 q1 = accS4[hw][k][1];
            const float4 q2 = accS4[hw][k][2];
            m0   = fmaf(q0.x, w.x, m0);
            ma0  = fmaf(q0.y, w.y, ma0);
            ma1  = fmaf(q0.z, w.y, ma1);
            ma2  = fmaf(q0.w, w.y, ma2);
            ms00 = fmaf(q1.x, w.z, ms00);
            ms01 = fmaf(q1.y, w.z, ms01);
            ms02 = fmaf(q1.z, w.z, ms02);
            ms11 = fmaf(q1.w, w.z, ms11);
            ms12 = fmaf(q2.x, w.z, ms12);
            ms22 = fmaf(q2.y, w.z, ms22);
        }

        // X via LDS transpose: write (u, i) at u*9+i (stride-9, conflict-free),
        // read back linearly, store 9 x 128B full lines.
        float* xs = xsS[hw];
        xs[u * 9 + 0] = f0 * m0 + f2 * ms00;
        xs[u * 9 + 1] = f1 * (-ma2) + f2 * ms01;
        xs[u * 9 + 2] = f1 * ( ma1) + f2 * ms02;
        xs[u * 9 + 3] = f1 * ( ma2) + f2 * ms01;
        xs[u * 9 + 4] = f0 * m0 + f2 * ms11;
        xs[u * 9 + 5] = f1 * (-ma0) + f2 * ms12;
        xs[u * 9 + 6] = f1 * (-ma1) + f2 * ms02;
        xs[u * 9 + 7] = f1 * ( ma0) + f2 * ms12;
        xs[u * 9 + 8] = f0 * m0 + f2 * ms22;

        float* xp = xout + (size_t)n * 288;
#pragma unroll
        for (int i = 0; i < 9; ++i)
            xp[i * 32 + u] = xs[i * 32 + u];
    }
}

extern "C" void kernel_launch(void* const* d_in, const int* in_sizes, int n_in,
                              void* d_out, int out_size, void* d_ws, size_t ws_size,
                              hipStream_t stream) {
    const int N = in_sizes[0];
    const int E = in_sizes[2];

    // Workspace (~31.8 MB, R5-R8 proven scale):
    //   acc N*320 f32 | P1 N*32 | P2 N*32 | Pt1 95*32 | Pt2 95*32
    //   | hist N | base N+1 | cursor N | perm E   (i32)
    float* acc  = (float*)d_ws;
    float* P1   = acc + (size_t)N * 320;
    float* P2   = P1 + (size_t)N * 32;
    float* Pt1  = P2 + (size_t)N * 32;
    float* Pt2  = Pt1 + 95 * 32;
    int*   hist = (int*)(Pt2 + 95 * 32);
    int*   basep  = hist + N;
    int*   cursor = basep + (N + 1);
    int*   perm   = cursor + N;

    float* xout  = (float*)d_out;              // [N][32][3][3] f32
    float* efeat = xout + (size_t)N * 288;     // [E][32] f32

    ptype_kernel<<<12, 256, 0, stream>>>(
        (const float*)d_in[6], (const float*)d_in[13], (const float*)d_in[14], Pt1, Pt2);

    prep_kernel<<<(N * 32 + 255) / 256, 256, 0, stream>>>(
        (const int*)d_in[0], Pt1, Pt2, P1, P2, hist, N);

    hist_kernel<<<(E + 255) / 256, 256, 0, stream>>>(
        (const int*)d_in[5], hist, E);

    scan_kernel<<<1, 64, 0, stream>>>(hist, basep, cursor, N, E);

    binperm_kernel<<<(E + 255) / 256, 256, 0, stream>>>(
        (const int*)d_in[5], cursor, perm, E);

    edge_csr_kernel<<<768, 256, 0, stream>>>(
        (const float*)d_in[1], (const float*)d_in[2], (const float*)d_in[3],
        (const int*)d_in[4],
        (const float*)d_in[7],  (const float*)d_in[8],
        (const float*)d_in[9],  (const float*)d_in[10],
        (const float*)d_in[11], (const float*)d_in[12],
        (const float*)d_in[15], (const float*)d_in[16],
        P1, P2, basep, perm,
        acc, efeat, N);

    node_kernel<<<512, 256, 0, stream>>>(
        acc,
        (const float*)d_in[17], (const float*)d_in[18], (const float*)d_in[19],
        (const float*)d_in[20], (const float*)d_in[21],
        (const float*)d_in[22], (const float*)d_in[23],
        (const float*)d_in[24], (const float*)d_in[25],
        xout, N);
}

// Round 10
// 539.633 us; speedup vs baseline: 1.3354x; 1.0641x over previous
//
#include <hip/hip_runtime.h>

// R15 = R14 resubmitted verbatim (R14 bench died to infra: "container failed
// twice"; source never ran). R14 rationale:
// R13 decomposition — edge_csr clean at 202us; the 370us remainder was
// (a) single-wave serial scan (~110us: 313 iters x ~900cyc on ONE wave) and
// (b) node kernel latency-bound at 25% occupancy (78KB LDS @ 256 threads).
// Fixes: 3-stage parallel scan (~15us); node at 512 threads / 73KB LDS
// (drop xsS scratch — u*9 scatter is L2-absorbed, full-line writeback anyway;
// ws2 repacked 32->24KB) -> 16 waves/CU. Edge kernel untouched.

#define EPW 8

// ---------------------------------------------------------------------------
// Prepass 1: per-TYPE We2 GEMV halves + zero the dst histogram.
// ---------------------------------------------------------------------------
__global__ void ptype_kernel(const float* __restrict__ emb,
                             const float* __restrict__ We2,
                             const float* __restrict__ be2,
                             float* __restrict__ Pt1, float* __restrict__ Pt2,
                             int* __restrict__ hist, int N) {
    const int gtid = blockIdx.x * 256 + threadIdx.x;
    for (int i = gtid; i < N; i += gridDim.x * 256) hist[i] = 0;
    const int c = threadIdx.x & 31;
    const int t = blockIdx.x * 8 + (threadIdx.x >> 5);
    if (t < 95) {
        float p1 = 0.f, p2 = 0.f;
        for (int k = 0; k < 32; ++k) {
            const float z = emb[t * 32 + k];
            p1 = fmaf(z, We2[k * 32 + c], p1);
            p2 = fmaf(z, We2[(32 + k) * 32 + c], p2);
        }
        Pt1[t * 32 + c] = p1 + be2[c];
        Pt2[t * 32 + c] = p2;
    }
}

// ---------------------------------------------------------------------------
// Prepass 2: gather per-node P1/P2 + dst histogram (hist zeroed in ptype).
// ---------------------------------------------------------------------------
__global__ void prep_kernel(const int* __restrict__ nt,
                            const float* __restrict__ Pt1, const float* __restrict__ Pt2,
                            const int* __restrict__ dst,
                            float* __restrict__ P1, float* __restrict__ P2,
                            int* __restrict__ hist, int N, int E) {
    const int i = blockIdx.x * 256 + threadIdx.x;
    if (i < E) atomicAdd(&hist[dst[i]], 1);
    if (i < N * 32) {
        const int n = i >> 5, c = i & 31;
        const int t = nt[n];
        P1[i] = Pt1[t * 32 + c];
        P2[i] = Pt2[t * 32 + c];
    }
}

// ---------------------------------------------------------------------------
// Parallel scan, 3 stages of wave-sized blocks (replaces the single-wave
// 313-iteration serial scan that idled the chip for ~110us).
// ---------------------------------------------------------------------------
__global__ void scanA_kernel(const int* __restrict__ hist, int* __restrict__ btot, int N) {
    const int lane = threadIdx.x;                 // 64
    const int i = blockIdx.x * 64 + lane;
    int v = (i < N) ? hist[i] : 0;
#pragma unroll
    for (int o = 1; o < 64; o <<= 1) v += __shfl_xor(v, o, 64);
    if (lane == 0) btot[blockIdx.x] = v;
}

__global__ void scanB_kernel(const int* __restrict__ btot, int* __restrict__ btotx,
                             int nb, int* __restrict__ baseN, int E) {
    const int lane = threadIdx.x;                 // 64
    int carry = 0;
    for (int s = 0; s < nb; s += 64) {
        const int i = s + lane;
        const int v = (i < nb) ? btot[i] : 0;
        int inc = v;
#pragma unroll
        for (int o = 1; o < 64; o <<= 1) {
            const int t = __shfl_up(inc, o, 64);
            if (lane >= o) inc += t;
        }
        if (i < nb) btotx[i] = carry + inc - v;
        carry += __shfl(inc, 63, 64);
    }
    if (lane == 0) *baseN = E;                    // base[N] = E
}

__global__ void scanC_kernel(const int* __restrict__ hist, const int* __restrict__ btotx,
                             int* __restrict__ base, int* __restrict__ cursor, int N) {
    const int lane = threadIdx.x;                 // 64
    const int i = blockIdx.x * 64 + lane;
    const int v = (i < N) ? hist[i] : 0;
    int inc = v;
#pragma unroll
    for (int o = 1; o < 64; o <<= 1) {
        const int t = __shfl_up(inc, o, 64);
        if (lane >= o) inc += t;
    }
    const int excl = btotx[blockIdx.x] + inc - v;
    if (i < N) { base[i] = excl; cursor[i] = excl; }
}

// perm[slot] = edge id, slots binned by dst (one int atomic per edge).
__global__ void binperm_kernel(const int* __restrict__ dst, int* __restrict__ cursor,
                               int* __restrict__ perm, int E) {
    const int i = blockIdx.x * 256 + threadIdx.x;
    if (i < E) {
        const int s = atomicAdd(&cursor[dst[i]], 1);
        perm[s] = i;
    }
}

// ---------------------------------------------------------------------------
// Edge CSR kernel [R13, unchanged — 202us, FETCH 62MB, WRITE 50MB, no spill]:
// wave-per-node grid-stride; R10 reg-weight engine; I/A/S in 10 registers;
// epilogue = plain coalesced stores (no atomics, no zero-pass).
// ---------------------------------------------------------------------------
__global__ __launch_bounds__(256) void edge_csr_kernel(
    const float* __restrict__ edge_attr,    // [E][64]
    const float* __restrict__ bond_dist,    // [E]
    const float* __restrict__ bond_vec,     // [E][3]
    const int*   __restrict__ src,
    const float* __restrict__ Wd1, const float* __restrict__ bd1,
    const float* __restrict__ Wd2, const float* __restrict__ bd2,
    const float* __restrict__ Wd3, const float* __restrict__ bd3,
    const float* __restrict__ We3, const float* __restrict__ be3,
    const float* __restrict__ P1,           // [N][32]
    const float* __restrict__ P2,           // [N][32]
    const int*   __restrict__ basep,        // [N+1]
    const int*   __restrict__ perm,         // [E]
    float* __restrict__ acc,                // [N][10][32]
    float* __restrict__ efeat,              // [E][32]
    int N)
{
    __shared__ float4 sX[4][8][16];

    const int tid  = threadIdx.x;
    const int lane = tid & 63;
    const int c    = lane & 31;
    const int h    = lane >> 5;
    const int wv   = tid >> 6;

    float w0r[32], w1r[32], w2r[32], w3r[32];
#pragma unroll
    for (int kk = 0; kk < 32; ++kk) {
        const int row = (h << 5) + kk;
        w0r[kk] = Wd1[row * 32 + c];
        w1r[kk] = Wd2[row * 32 + c];
        w2r[kk] = Wd3[row * 32 + c];
        w3r[kk] = We3[row * 32 + c];
    }
    const float bd1r = bd1[c], bd2r = bd2[c], bd3r = bd3[c], be3r = be3[c];

    const int wgid   = blockIdx.x * 4 + wv;
    const int nwaves = gridDim.x * 4;

    for (int n = wgid; n < N; n += nwaves) {
        const int js = basep[n], je = basep[n + 1];
        const float pzn = P2[(size_t)n * 32 + c];

        float rc0 = 0, ra0 = 0, ra1 = 0, ra2 = 0;
        float rs00 = 0, rs01 = 0, rs02 = 0, rs11 = 0, rs12 = 0, rs22 = 0;

        for (int off = js; off < je; off += EPW) {
            int eid4[4], si4[4]; float dd[4], vx[4], vy[4], vz[4]; bool vld[4];
#pragma unroll
            for (int jj = 0; jj < 4; ++jj) {
                int s_ = off + jj + (h << 2);
                vld[jj] = (s_ < je);
                if (s_ > je - 1) s_ = je - 1;
                const int eid = perm[s_];
                eid4[jj] = eid;
                si4[jj]  = src[eid];
                dd[jj]   = bond_dist[eid];
                vx[jj]   = bond_vec[3 * (size_t)eid + 0];
                vy[jj]   = bond_vec[3 * (size_t)eid + 1];
                vz[jj]   = bond_vec[3 * (size_t)eid + 2];
            }

            {
                int sa = off + (lane >> 4);     if (sa > je - 1) sa = je - 1;
                int sb = off + 4 + (lane >> 4); if (sb > je - 1) sb = je - 1;
                const int ea = perm[sa], eb = perm[sb];
                sX[wv][lane >> 4][lane & 15] =
                    *(const float4*)&edge_attr[(size_t)ea * 64 + (lane & 15) * 4];
                sX[wv][4 + (lane >> 4)][lane & 15] =
                    *(const float4*)&edge_attr[(size_t)eb * 64 + (lane & 15) * 4];
            }

            float A0[EPW], A1[EPW], A2[EPW], A3[EPW];
#pragma unroll
            for (int j = 0; j < EPW; ++j) { A0[j] = 0.f; A1[j] = 0.f; A2[j] = 0.f; A3[j] = 0.f; }

#pragma unroll
            for (int kq = 0; kq < 8; ++kq) {
                const int k0 = kq * 4;
#pragma unroll
                for (int j = 0; j < EPW; ++j) {
                    const float4 xq = sX[wv][j][(h << 3) + kq];
                    A0[j] = fmaf(xq.x, w0r[k0 + 0], A0[j]);
                    A0[j] = fmaf(xq.y, w0r[k0 + 1], A0[j]);
                    A0[j] = fmaf(xq.z, w0r[k0 + 2], A0[j]);
                    A0[j] = fmaf(xq.w, w0r[k0 + 3], A0[j]);
                    A1[j] = fmaf(xq.x, w1r[k0 + 0], A1[j]);
                    A1[j] = fmaf(xq.y, w1r[k0 + 1], A1[j]);
                    A1[j] = fmaf(xq.z, w1r[k0 + 2], A1[j]);
                    A1[j] = fmaf(xq.w, w1r[k0 + 3], A1[j]);
                    A2[j] = fmaf(xq.x, w2r[k0 + 0], A2[j]);
                    A2[j] = fmaf(xq.y, w2r[k0 + 1], A2[j]);
                    A2[j] = fmaf(xq.z, w2r[k0 + 2], A2[j]);
                    A2[j] = fmaf(xq.w, w2r[k0 + 3], A2[j]);
                    A3[j] = fmaf(xq.x, w3r[k0 + 0], A3[j]);
                    A3[j] = fmaf(xq.y, w3r[k0 + 1], A3[j]);
                    A3[j] = fmaf(xq.z, w3r[k0 + 2], A3[j]);
                    A3[j] = fmaf(xq.w, w3r[k0 + 3], A3[j]);
                }
            }

            float az4[4];
#pragma unroll
            for (int jj = 0; jj < 4; ++jj)
                az4[jj] = P1[(size_t)si4[jj] * 32 + c] + pzn;

#pragma unroll
            for (int jj = 0; jj < 4; ++jj) {
                const float sd0 = h ? A0[jj] : A0[jj + 4];
                const float sd1 = h ? A1[jj] : A1[jj + 4];
                const float sd2 = h ? A2[jj] : A2[jj + 4];
                const float sd3 = h ? A3[jj] : A3[jj + 4];
                const float mn0 = h ? A0[jj + 4] : A0[jj];
                const float mn1 = h ? A1[jj + 4] : A1[jj];
                const float mn2 = h ? A2[jj + 4] : A2[jj];
                const float mn3 = h ? A3[jj + 4] : A3[jj];
                const float t0 = mn0 + __shfl_xor(sd0, 32);
                const float t1 = mn1 + __shfl_xor(sd1, 32);
                const float t2 = mn2 + __shfl_xor(sd2, 32);
                const float t3 = mn3 + __shfl_xor(sd3, 32);

                const float d = dd[jj];
                const float C = (d <= 5.0f) ? 0.5f * (cosf(3.14159265358979323846f * d / 5.0f) + 1.0f) : 0.0f;
                float v0 = vx[jj], v1 = vy[jj], v2 = vz[jj];
                const float inv = 1.0f / sqrtf(v0 * v0 + v1 * v1 + v2 * v2);
                v0 *= inv; v1 *= inv; v2 *= inv;
                const float tr3 = (v0 * v0 + v1 * v1 + v2 * v2) * (1.0f / 3.0f);
                const float y00 = v0 * v0 - tr3, y11 = v1 * v1 - tr3, y22 = v2 * v2 - tr3;
                const float y01 = v0 * v1, y02 = v0 * v2, y12 = v1 * v2;

                const float az = az4[jj];
                const float a1v = t0 + bd1r;
                const float a2v = t1 + bd2r;
                const float a3v = t2 + bd3r;
                const float a4v = t3 + be3r;
                const float w1v = a1v * C, w2v = a2v * C, w3v = a3v * C;
                const float fI = az * w1v, fA = az * w2v, fS = az * w3v;

                if (vld[jj]) {
                    efeat[(size_t)eid4[jj] * 32 + c] = a4v;
                    rc0 += fI;
                    ra0 = fmaf(fA, v0, ra0);
                    ra1 = fmaf(fA, v1, ra1);
                    ra2 = fmaf(fA, v2, ra2);
                    rs00 = fmaf(fS, y00, rs00);
                    rs01 = fmaf(fS, y01, rs01);
                    rs02 = fmaf(fS, y02, rs02);
                    rs11 = fmaf(fS, y11, rs11);
                    rs12 = fmaf(fS, y12, rs12);
                    rs22 = fmaf(fS, y22, rs22);
                }
            }
        }

        rc0 += __shfl_xor(rc0, 32);  ra0 += __shfl_xor(ra0, 32);
        ra1 += __shfl_xor(ra1, 32);  ra2 += __shfl_xor(ra2, 32);
        rs00 += __shfl_xor(rs00, 32); rs01 += __shfl_xor(rs01, 32);
        rs02 += __shfl_xor(rs02, 32); rs11 += __shfl_xor(rs11, 32);
        rs12 += __shfl_xor(rs12, 32); rs22 += __shfl_xor(rs22, 32);

        float* ap = acc + (size_t)n * 320;
        if (h == 0) {
            ap[c]       = rc0;  ap[32 + c]  = ra0;  ap[64 + c]  = ra1;
            ap[96 + c]  = ra2;  ap[128 + c] = rs00;
        } else {
            ap[160 + c] = rs01; ap[192 + c] = rs02; ap[224 + c] = rs11;
            ap[256 + c] = rs12; ap[288 + c] = rs22;
        }
    }
}

// ---------------------------------------------------------------------------
// Node kernel v4 [R14]: 512 threads (16 half-waves), LDS 73KB -> 2 blocks/CU
// = 16 waves/CU (was 8). xsS dropped (direct u*9 stores — L2 absorbs, full
// 1152B/node written so HBM writeback is full-line). ws2 as 3 scalar arrays.
// ---------------------------------------------------------------------------
__global__ __launch_bounds__(512) void node_kernel(
    const float* __restrict__ acc,          // [N][10][32]
    const float* __restrict__ Wt0, const float* __restrict__ Wt1, const float* __restrict__ Wt2,
    const float* __restrict__ Ws1, const float* __restrict__ bs1,
    const float* __restrict__ Ws2, const float* __restrict__ bs2,
    const float* __restrict__ lng, const float* __restrict__ lnb,
    float* __restrict__ xout,               // [N][32][3][3]
    int N)
{
    __shared__ float4 wtp[32][32];          // 16 KB {Wt0,Wt1,Wt2,-}
    __shared__ float2 ws1p[32][32];         // 8 KB
    __shared__ float  ws2a[64][32];         // 8 KB  Ws2[k][3u]
    __shared__ float  ws2b[64][32];         // 8 KB  Ws2[k][3u+1]
    __shared__ float  ws2c[64][32];         // 8 KB  Ws2[k][3u+2]
    __shared__ float4 accS4[16][32][3];     // 24 KB (per half-wave private)
    __shared__ float2 sb1p[32];
    __shared__ float4 sb2p[32];
    __shared__ float  sg[32], sbv[32];

    const int tid = threadIdx.x;
    for (int i = tid; i < 1024; i += 512) {
        const int k = i >> 5, u = i & 31;
        wtp[k][u]  = make_float4(Wt0[i], Wt1[i], Wt2[i], 0.f);
        ws1p[k][u] = make_float2(Ws1[k * 64 + u], Ws1[k * 64 + 32 + u]);
    }
    for (int i = tid; i < 2048; i += 512) {
        const int k = i >> 5, u = i & 31;
        ws2a[k][u] = Ws2[k * 96 + 3 * u];
        ws2b[k][u] = Ws2[k * 96 + 3 * u + 1];
        ws2c[k][u] = Ws2[k * 96 + 3 * u + 2];
    }
    if (tid < 32) {
        sb1p[tid] = make_float2(bs1[tid], bs1[tid + 32]);
        sb2p[tid] = make_float4(bs2[3 * tid], bs2[3 * tid + 1], bs2[3 * tid + 2], 0.f);
        sg[tid] = lng[tid]; sbv[tid] = lnb[tid];
    }
    __syncthreads();   // the only barrier

    const int hw = tid >> 5, u = tid & 31;
    const int stride = gridDim.x * 16;

    for (int n = blockIdx.x * 16 + hw; n < N; n += stride) {
        const float* ap = acc + (size_t)n * 320 + u;
        const float c0 = ap[0],   a0 = ap[32],  a1 = ap[64],  a2 = ap[96];
        const float s00 = ap[128], s01 = ap[160], s02 = ap[192];
        const float s11 = ap[224], s12 = ap[256], s22 = ap[288];

        accS4[hw][u][0] = make_float4(c0, a0, a1, a2);
        accS4[hw][u][1] = make_float4(s00, s01, s02, s11);
        accS4[hw][u][2] = make_float4(s12, s22, 0.f, 0.f);

        const float m00 = c0 + s00, m11 = c0 + s11, m22 = c0 + s22;
        float nrm = m00 * m00 + m11 * m11 + m22 * m22
                  + 2.0f * (s01 * s01 + a2 * a2 + s02 * s02 + a1 * a1 + s12 * s12 + a0 * a0);

        float sum = nrm;
#pragma unroll
        for (int o = 16; o >= 1; o >>= 1) sum += __shfl_xor(sum, o, 32);
        const float mu = sum * (1.0f / 32.0f);
        const float dv = nrm - mu;
        float vs = dv * dv;
#pragma unroll
        for (int o = 16; o >= 1; o >>= 1) vs += __shfl_xor(vs, o, 32);
        const float var = vs * (1.0f / 32.0f);
        const float nl = dv * rsqrtf(var + 1e-5f) * sg[u] + sbv[u];

        const float2 b1 = sb1p[u];
        float h1a = b1.x, h1b = b1.y;
#pragma unroll
        for (int k = 0; k < 32; ++k) {
            const float x = __shfl(nl, k, 32);
            const float2 wq = ws1p[k][u];
            h1a = fmaf(x, wq.x, h1a);
            h1b = fmaf(x, wq.y, h1b);
        }
        h1a = h1a / (1.0f + __expf(-h1a));
        h1b = h1b / (1.0f + __expf(-h1b));

        const float4 b2 = sb2p[u];
        float f0 = b2.x, f1 = b2.y, f2 = b2.z;
#pragma unroll
        for (int k = 0; k < 32; ++k) {
            const float hh = __shfl(h1a, k, 32);
            f0 = fmaf(hh, ws2a[k][u], f0);
            f1 = fmaf(hh, ws2b[k][u], f1);
            f2 = fmaf(hh, ws2c[k][u], f2);
        }
#pragma unroll
        for (int k = 0; k < 32; ++k) {
            const float hh = __shfl(h1b, k, 32);
            f0 = fmaf(hh, ws2a[32 + k][u], f0);
            f1 = fmaf(hh, ws2b[32 + k][u], f1);
            f2 = fmaf(hh, ws2c[32 + k][u], f2);
        }
        f0 = f0 / (1.0f + __expf(-f0));
        f1 = f1 / (1.0f + __expf(-f1));
        f2 = f2 / (1.0f + __expf(-f2));

        float m0 = 0, ma0 = 0, ma1 = 0, ma2 = 0;
        float ms00 = 0, ms01 = 0, ms02 = 0, ms11 = 0, ms12 = 0, ms22 = 0;
#pragma unroll
        for (int k = 0; k < 32; ++k) {
            const float4 w  = wtp[k][u];
            const float4 q0 = accS4[hw][k][0];
            const float4 q1 = accS4[hw][k][1];
            const float4 q2 = accS4[hw][k][2];
            m0   = fmaf(q0.x, w.x, m0);
            ma0  = fmaf(q0.y, w.y, ma0);
            ma1  = fmaf(q0.z, w.y, ma1);
            ma2  = fmaf(q0.w, w.y, ma2);
            ms00 = fmaf(q1.x, w.z, ms00);
            ms01 = fmaf(q1.y, w.z, ms01);
            ms02 = fmaf(q1.z, w.z, ms02);
            ms11 = fmaf(q1.w, w.z, ms11);
            ms12 = fmaf(q2.x, w.z, ms12);
            ms22 = fmaf(q2.y, w.z, ms22);
        }

        float* xp = xout + (size_t)n * 288 + u * 9;
        xp[0] = f0 * m0 + f2 * ms00;
        xp[1] = f1 * (-ma2) + f2 * ms01;
        xp[2] = f1 * ( ma1) + f2 * ms02;
        xp[3] = f1 * ( ma2) + f2 * ms01;
        xp[4] = f0 * m0 + f2 * ms11;
        xp[5] = f1 * (-ma0) + f2 * ms12;
        xp[6] = f1 * (-ma1) + f2 * ms02;
        xp[7] = f1 * ( ma0) + f2 * ms12;
        xp[8] = f0 * m0 + f2 * ms22;
    }
}

extern "C" void kernel_launch(void* const* d_in, const int* in_sizes, int n_in,
                              void* d_out, int out_size, void* d_ws, size_t ws_size,
                              hipStream_t stream) {
    const int N = in_sizes[0];
    const int E = in_sizes[2];
    const int NB = (N + 63) / 64;              // scan chunk count (313)

    // Workspace (~32 MB): acc N*320 f32 | P1 N*32 | P2 N*32 | Pt1 | Pt2
    //   | hist N | base N+1 | cursor N | perm E | btot NB | btotx NB (i32)
    float* acc  = (float*)d_ws;
    float* P1   = acc + (size_t)N * 320;
    float* P2   = P1 + (size_t)N * 32;
    float* Pt1  = P2 + (size_t)N * 32;
    float* Pt2  = Pt1 + 95 * 32;
    int*   hist = (int*)(Pt2 + 95 * 32);
    int*   basep  = hist + N;
    int*   cursor = basep + (N + 1);
    int*   perm   = cursor + N;
    int*   btot   = perm + E;
    int*   btotx  = btot + NB;

    float* xout  = (float*)d_out;              // [N][32][3][3] f32
    float* efeat = xout + (size_t)N * 288;     // [E][32] f32

    ptype_kernel<<<12, 256, 0, stream>>>(
        (const float*)d_in[6], (const float*)d_in[13], (const float*)d_in[14],
        Pt1, Pt2, hist, N);

    prep_kernel<<<(N * 32 + 255) / 256, 256, 0, stream>>>(
        (const int*)d_in[0], Pt1, Pt2, (const int*)d_in[5], P1, P2, hist, N, E);

    scanA_kernel<<<NB, 64, 0, stream>>>(hist, btot, N);
    scanB_kernel<<<1, 64, 0, stream>>>(btot, btotx, NB, basep + N, E);
    scanC_kernel<<<NB, 64, 0, stream>>>(hist, btotx, basep, cursor, N);

    binperm_kernel<<<(E + 255) / 256, 256, 0, stream>>>(
        (const int*)d_in[5], cursor, perm, E);

    edge_csr_kernel<<<768, 256, 0, stream>>>(
        (const float*)d_in[1], (const float*)d_in[2], (const float*)d_in[3],
        (const int*)d_in[4],
        (const float*)d_in[7],  (const float*)d_in[8],
        (const float*)d_in[9],  (const float*)d_in[10],
        (const float*)d_in[11], (const float*)d_in[12],
        (const float*)d_in[15], (const float*)d_in[16],
        P1, P2, basep, perm,
        acc, efeat, N);

    node_kernel<<<512, 512, 0, stream>>>(
        acc,
        (const float*)d_in[17], (const float*)d_in[18], (const float*)d_in[19],
        (const float*)d_in[20], (const float*)d_in[21],
        (const float*)d_in[22], (const float*)d_in[23],
        (const float*)d_in[24], (const float*)d_in[25],
        xout, N);
}